// Round 15
// baseline (291.351 us; speedup 1.0000x reference)
//
#include <hip/hip_runtime.h>

#define B_ 2
#define T_ 2048
#define C_ 1024
#define H_ 16
#define DH_ 64
#define N3_ 3072
#define BT_ 4096   // B_*T_

typedef __attribute__((ext_vector_type(4))) float f32x4;
typedef __attribute__((ext_vector_type(8))) short short8;
typedef __attribute__((ext_vector_type(4))) unsigned short us4;
typedef __attribute__((ext_vector_type(4))) unsigned int u32x4;

// HW bf16 convert (RNE)
__device__ __forceinline__ unsigned short f2bf(float f) {
  return __builtin_bit_cast(unsigned short, (__bf16)f);
}

__device__ __forceinline__ float bf2f(unsigned short s) {
  unsigned int u = ((unsigned int)s) << 16;
  return __builtin_bit_cast(float, u);
}

// pack 2 f32 -> 2 bf16 in one u32 (lo = a, hi = b)
__device__ __forceinline__ unsigned int cvtpk(float a, float b) {
  unsigned int r;
  asm("v_cvt_pk_bf16_f32 %0, %1, %2" : "=v"(r) : "v"(a), "v"(b));
  return r;
}

__device__ __forceinline__ void gload16(const void* g, void* l) {
  __builtin_amdgcn_global_load_lds(
      (const __attribute__((address_space(1))) unsigned int*)g,
      (__attribute__((address_space(3))) unsigned int*)l, 16, 0, 0);
}

// raw barrier: drain LDS ops only; leave global loads/stores in flight
__device__ __forceinline__ void lds_barrier() {
  asm volatile("s_waitcnt lgkmcnt(0)" ::: "memory");
  __builtin_amdgcn_s_barrier();
}

// exp scale: 1/sqrt(64) * log2(e), folded into q so softmax exp becomes bare v_exp_f32 (exp2)
#define QSCALE 0.1803368801111137f

// ---------------- K0: fused prep (x cvt + both W transposes) ----------------
__global__ __launch_bounds__(256) void prep_kernel(const float* __restrict__ x,
                                                   const float* __restrict__ W_qkv,
                                                   const float* __restrict__ W_out,
                                                   unsigned short* __restrict__ xb,
                                                   unsigned short* __restrict__ wqkvT,
                                                   unsigned short* __restrict__ woutT) {
  __shared__ float tile[32][33];
  int b = blockIdx.x;
  if (b < 4096) {
    size_t i = (size_t)b * 256 + threadIdx.x;
    float4 v = *(const float4*)(x + i * 4);
    us4 o = {f2bf(v.x), f2bf(v.y), f2bf(v.z), f2bf(v.w)};
    *(us4*)(xb + i * 4) = o;
    return;
  }
  const float* W;
  unsigned short* Wt;
  int Ncols, bx, by;
  if (b < 4096 + 3072) {
    int bb = b - 4096;
    W = W_qkv; Wt = wqkvT; Ncols = 3072; bx = bb % 96; by = bb / 96;
  } else {
    int bb = b - 7168;
    W = W_out; Wt = woutT; Ncols = 1024; bx = bb % 32; by = bb / 32;
  }
  int n0 = bx * 32, k0 = by * 32;
  int tx = threadIdx.x & 31, ty = threadIdx.x >> 5;
#pragma unroll
  for (int i = 0; i < 4; ++i) {
    int k = k0 + ty + i * 8;
    tile[ty + i * 8][tx] = W[(size_t)k * Ncols + n0 + tx];
  }
  __syncthreads();
#pragma unroll
  for (int i = 0; i < 4; ++i) {
    int n = n0 + ty + i * 8;
    Wt[(size_t)n * 1024 + k0 + tx] = f2bf(tile[tx][ty + i * 8]);
  }
}

// ---------------- K1/K3: 128xBN x32 bf16 MFMA GEMM (R6 BK=32 version) ----------------
template <int MODE, int BN>
__global__ __launch_bounds__(256) void gemm_kernel(
    const unsigned short* __restrict__ A, const unsigned short* __restrict__ Bt,
    const float* __restrict__ bias, unsigned short* __restrict__ q_ws,
    unsigned short* __restrict__ k_ws, unsigned short* __restrict__ vt_ws,
    float* __restrict__ yout) {
  __shared__ unsigned short lds_a[128 * 32];
  __shared__ unsigned short lds_b[BN * 32];
  const int tid = threadIdx.x;
  const int w = tid >> 6, l = tid & 63;
  const int m0 = blockIdx.y * 128;
  const int n0 = blockIdx.x * BN;
  const int wr = (w >> 1) * 64, wc = (w & 1) * (BN / 2);
  constexpr int NI = BN / 32;
  const int K = 1024;

  f32x4 acc[4][NI] = {};
  for (int k0 = 0; k0 < K; k0 += 32) {
    __syncthreads();
#pragma unroll
    for (int i = 0; i < 2; ++i) {
      int li = i * 256 + tid;
      int row = li >> 2, cl = li & 3, cs = cl ^ (row & 3);
      gload16((const char*)A + ((size_t)(m0 + row) * K + k0) * 2 + cs * 16,
              (char*)lds_a + li * 16);
    }
#pragma unroll
    for (int i = 0; i < BN / 64; ++i) {
      int li = i * 256 + tid;
      int row = li >> 2, cl = li & 3, cs = cl ^ (row & 3);
      gload16((const char*)Bt + ((size_t)(n0 + row) * K + k0) * 2 + cs * 16,
              (char*)lds_b + li * 16);
    }
    __syncthreads();
    short8 af[4], bfr[NI];
#pragma unroll
    for (int mi = 0; mi < 4; ++mi) {
      int m = wr + mi * 16 + (l & 15);
      af[mi] = *(const short8*)((const char*)lds_a + m * 64 + (((l >> 4) ^ (m & 3)) * 16));
    }
#pragma unroll
    for (int ni = 0; ni < NI; ++ni) {
      int n = wc + ni * 16 + (l & 15);
      bfr[ni] = *(const short8*)((const char*)lds_b + n * 64 + (((l >> 4) ^ (n & 3)) * 16));
    }
#pragma unroll
    for (int mi = 0; mi < 4; ++mi)
#pragma unroll
      for (int ni = 0; ni < NI; ++ni)
        acc[mi][ni] = __builtin_amdgcn_mfma_f32_16x16x32_bf16(af[mi], bfr[ni], acc[mi][ni], 0, 0, 0);
  }

  float bi[NI];
#pragma unroll
  for (int ni = 0; ni < NI; ++ni) bi[ni] = bias[n0 + wc + ni * 16 + (l & 15)];

  if (MODE == 1) {
#pragma unroll
    for (int mi = 0; mi < 4; ++mi) {
#pragma unroll
      for (int ni = 0; ni < NI; ++ni) {
        int n = n0 + wc + ni * 16 + (l & 15);
#pragma unroll
        for (int r = 0; r < 4; ++r) {
          int m = m0 + wr + mi * 16 + ((l >> 4) << 2) + r;
          yout[(size_t)m * 1024 + n] = acc[mi][ni][r] + bi[ni];
        }
      }
    }
  } else {
    int sec = (n0 + wc) >> 10;  // uniform per half-tile: 0=q 1=k 2=v
#pragma unroll
    for (int mi = 0; mi < 4; ++mi) {
#pragma unroll
      for (int ni = 0; ni < NI; ++ni) {
        int n = n0 + wc + ni * 16 + (l & 15);
        int nn = n & 1023, h = nn >> 6, d = nn & 63;
        if (sec == 2) {
          int mbase = m0 + wr + mi * 16 + ((l >> 4) << 2);
          int bb = mbase >> 11, t = mbase & 2047;
          us4 o;
#pragma unroll
          for (int r = 0; r < 4; ++r) o[r] = f2bf(acc[mi][ni][r] + bi[ni]);
          *(us4*)(vt_ws + ((size_t)(bb * 16 + h) * 64 + d) * 2048 + t) = o;
        } else {
#pragma unroll
          for (int r = 0; r < 4; ++r) {
            int m = m0 + wr + mi * 16 + ((l >> 4) << 2) + r;
            int bb = m >> 11, t = m & 2047;
            float v = acc[mi][ni][r] + bi[ni];
            size_t idx = ((size_t)(bb * 16 + h) * 2048 + t) * 64 + d;
            if (sec == 0)
              q_ws[idx] = f2bf(v * QSCALE);  // fold 1/sqrt(64)*log2e into q
            else
              k_ws[idx] = f2bf(v);
          }
        }
      }
    }
  }
}

// ---------------- K2: causal attention, swapped QK^T; fill overlapped with COUNTED vmcnt ----------------
__global__ __launch_bounds__(512) void attn_kernel(
    const unsigned short* __restrict__ q_ws, const unsigned short* __restrict__ k_ws,
    const unsigned short* __restrict__ vt_ws, float* __restrict__ att,
    unsigned short* __restrict__ yh) {
  __shared__ unsigned short lds_k[64 * 64];
  __shared__ unsigned short lds_v[64 * 64];
  const int tid = threadIdx.x, w = tid >> 6, l = tid & 63;
  const int id = blockIdx.x;
  const int rr = id >> 8, j = id & 255;
  int qt = j & 15;
  if (rr) qt = 15 - qt;
  const int bh = (j >> 4) + (rr << 4);
  const int q0 = qt * 128;
  const size_t hoff = (size_t)bh * (2048 * 64);
  const char* kbase = (const char*)k_ws + hoff * 2;
  const char* vbase = (const char*)vt_ws + hoff * 2;
  float* attb = att + (size_t)bh * 2048 * 2048;

  auto stageK = [&](int kt) {
    int row = tid >> 3, cl = tid & 7, cs = cl ^ (row & 7);
    gload16(kbase + (size_t)kt * 8192 + row * 128 + cs * 16, (char*)lds_k + tid * 16);
  };
  auto stageV = [&](int kt) {
    int row = tid >> 3, cl = tid & 7, cs = cl ^ (row & 7);
    gload16(vbase + (size_t)row * 4096 + kt * 128 + cs * 16, (char*)lds_v + tid * 16);
  };

  short8 qf[2];
  {
    int row = q0 + w * 16 + (l & 15);
    const char* qb = (const char*)q_ws + (hoff + (size_t)row * 64) * 2;
    qf[0] = *(const short8*)(qb + ((l >> 4) * 16));
    qf[1] = *(const short8*)(qb + 64 + ((l >> 4) * 16));
  }

  // swapped layout: this lane's q-row and per-value k-cols
  const int qrow = q0 + w * 16 + (l & 15);          // q-row owned by this lane (C col index)
  const int kcolbase = (l >> 4) << 2;               // + ni*16 + r gives local k-col
  const int nkt = 2 * qt + 2;

  // ---- pass 1: per-lane scalar row-sum of exp2(s'), with upper-triangle zero-fill
  //      interleaved via COUNTED vmcnt (stores stay in flight across the barrier) ----
  float lsum = 0.f;
  const int fillTotal = 30 - 2 * qt;  // 64-col stripes right of this q-band
  int fillDone = 0;
  const int fillRow = q0 + (tid >> 2);
  const int fillColB = ((tid & 3) << 4) + (qt << 7) + 128;  // cstart + (tid&3)*16
  for (int kt = 0; kt < nkt; ++kt) {
    lds_barrier();
    stageK(kt);
    if (fillDone < fillTotal) {
      // one 32KB stripe: 4 f32x4/thread, 256B contiguous per row
      f32x4 z = {0.f, 0.f, 0.f, 0.f};
      float* dst = attb + (size_t)fillRow * 2048 + fillColB + fillDone * 64;
#pragma unroll
      for (int u = 0; u < 4; ++u) *(f32x4*)(dst + u * 4) = z;
      ++fillDone;
      // 4 newest (stores) may remain outstanding; older stageK load must be done
      asm volatile("s_waitcnt vmcnt(4)" ::: "memory");
    } else {
      asm volatile("s_waitcnt vmcnt(0)" ::: "memory");
    }
    __builtin_amdgcn_s_barrier();
    const bool diag = (kt >= 2 * qt);
    f32x4 s[4] = {};
#pragma unroll
    for (int ni = 0; ni < 4; ++ni) {
      int jj = ni * 16 + (l & 15);
#pragma unroll
      for (int cc = 0; cc < 2; ++cc) {
        short8 kf = *(const short8*)((const char*)lds_k + jj * 128 +
                                     (((cc * 4 + (l >> 4)) ^ (jj & 7)) * 16));
        s[ni] = __builtin_amdgcn_mfma_f32_16x16x32_bf16(kf, qf[cc], s[ni], 0, 0, 0);
      }
    }
#pragma unroll
    for (int ni = 0; ni < 4; ++ni) {
#pragma unroll
      for (int r = 0; r < 4; ++r) {
        float e = __builtin_exp2f(s[ni][r]);
        if (diag) {
          int colg = kt * 64 + ni * 16 + kcolbase + r;
          if (colg > qrow) e = 0.f;
        }
        lsum += e;
      }
    }
  }
  // tail: remaining stripes burst with no wait — stream during reduce/pass-2 prologue
  {
    f32x4 z = {0.f, 0.f, 0.f, 0.f};
    for (; fillDone < fillTotal; ++fillDone) {
      float* dst = attb + (size_t)fillRow * 2048 + fillColB + fillDone * 64;
#pragma unroll
      for (int u = 0; u < 4; ++u) *(f32x4*)(dst + u * 4) = z;
    }
  }

  // row q (=l&15 group) lives in lanes {q, q+16, q+32, q+48}: 2-shuffle reduce
  lsum += __shfl_xor(lsum, 16);
  lsum += __shfl_xor(lsum, 32);
  const float invl = 1.0f / lsum;  // lane-native for q-row (l&15)

  // ---- pass 2: recompute (swapped), direct f32 att stores, in-register P->PV ----
  // P is normalized BEFORE the PV MFMA, so yacc needs no epilogue scaling.
  f32x4 yacc[4] = {};
  const int srcA = (l & 15) + ((l >> 4) & 1) * 32;  // holder of t=0..3 cell
  const int srcB = srcA + 16;                        // holder of t=4..7 cell
  const bool hiSel = ((l >> 4) >> 1) & 1;            // hi>=2 consumers take ni=2kk+1

  auto step2 = [&](int kt, bool diag) {
    lds_barrier();
    stageK(kt);
    stageV(kt);
    __syncthreads();
    f32x4 s[4] = {};
#pragma unroll
    for (int ni = 0; ni < 4; ++ni) {
      int jj = ni * 16 + (l & 15);
#pragma unroll
      for (int cc = 0; cc < 2; ++cc) {
        short8 kf = *(const short8*)((const char*)lds_k + jj * 128 +
                                     (((cc * 4 + (l >> 4)) ^ (jj & 7)) * 16));
        s[ni] = __builtin_amdgcn_mfma_f32_16x16x32_bf16(kf, qf[cc], s[ni], 0, 0, 0);
      }
    }
    // normalize, mask, store att (float4 of 4 consecutive cols), pack bf16 pairs
    unsigned int W0[4], W1[4];
#pragma unroll
    for (int ni = 0; ni < 4; ++ni) {
      f32x4 p;
#pragma unroll
      for (int r = 0; r < 4; ++r) {
        float v = __builtin_exp2f(s[ni][r]) * invl;
        if (diag) {
          int colg = kt * 64 + ni * 16 + kcolbase + r;
          if (colg > qrow) v = 0.f;
        }
        p[r] = v;
      }
      *(f32x4*)(attb + (size_t)qrow * 2048 + kt * 64 + ni * 16 + kcolbase) = p;
      W0[ni] = cvtpk(p[0], p[1]);
      W1[ni] = cvtpk(p[2], p[3]);
    }
    // redistribute P into PV A-fragments:
    // consumer (q=l&15, hi=l>>4), col c = kk*32+hi*8+t: source reg ni=2kk+(hi>>1),
    // source lane q+32*(hi&1) for t<4 (srcA) else +16 (srcB), W0/W1 by t&3.
#pragma unroll
    for (int kk = 0; kk < 2; ++kk) {
      unsigned int a0 = __shfl(W0[2 * kk], srcA), a0b = __shfl(W0[2 * kk + 1], srcA);
      unsigned int a1 = __shfl(W1[2 * kk], srcA), a1b = __shfl(W1[2 * kk + 1], srcA);
      unsigned int b0 = __shfl(W0[2 * kk], srcB), b0b = __shfl(W0[2 * kk + 1], srcB);
      unsigned int b1 = __shfl(W1[2 * kk], srcB), b1b = __shfl(W1[2 * kk + 1], srcB);
      u32x4 F = {hiSel ? a0b : a0, hiSel ? a1b : a1, hiSel ? b0b : b0, hiSel ? b1b : b1};
      short8 pf = __builtin_bit_cast(short8, F);
#pragma unroll
      for (int ni = 0; ni < 4; ++ni) {
        int d = ni * 16 + (l & 15);
        short8 vf = *(const short8*)((const char*)lds_v + d * 128 +
                                     (((kk * 4 + (l >> 4)) ^ (d & 7)) * 16));
        yacc[ni] = __builtin_amdgcn_mfma_f32_16x16x32_bf16(pf, vf, yacc[ni], 0, 0, 0);
      }
    }
  };
  for (int kt = 0; kt < 2 * qt; ++kt) step2(kt, false);
  step2(2 * qt, true);
  step2(2 * qt + 1, true);

  // y_heads write: [B][T][H*64] bf16 (yacc already normalized — P carried invl)
  {
    int bb = bh >> 4, h = bh & 15;
#pragma unroll
    for (int ni = 0; ni < 4; ++ni) {
      int d = ni * 16 + (l & 15);
#pragma unroll
      for (int r = 0; r < 4; ++r) {
        int t = q0 + w * 16 + ((l >> 4) << 2) + r;
        yh[((size_t)bb * 2048 + t) * 1024 + h * 64 + d] = f2bf(yacc[ni][r]);
      }
    }
  }
}

// ---------------- launch ----------------
extern "C" void kernel_launch(void* const* d_in, const int* in_sizes, int n_in,
                              void* d_out, int out_size, void* d_ws, size_t ws_size,
                              hipStream_t stream) {
  const float* x = (const float*)d_in[0];
  const float* W_qkv = (const float*)d_in[1];
  const float* b_qkv = (const float*)d_in[2];
  const float* W_out = (const float*)d_in[3];
  const float* b_out = (const float*)d_in[4];
  float* out = (float*)d_out;

  char* ws = (char*)d_ws;
  unsigned short* xb = (unsigned short*)(ws);                        // 8 MB
  unsigned short* wqkvT = (unsigned short*)(ws + 8388608);           // 6 MB
  unsigned short* woutT = (unsigned short*)(ws + 14680064);          // 2 MB
  unsigned short* q_ws = (unsigned short*)(ws + 16777216);           // 8 MB
  unsigned short* k_ws = (unsigned short*)(ws + 25165824);           // 8 MB
  unsigned short* vt_ws = (unsigned short*)(ws + 33554432);          // 8 MB
  unsigned short* yh_ws = (unsigned short*)(ws + 41943040);          // 8 MB

  float* y_out = out;                       // [4096][1024]
  float* att_out = out + (size_t)BT_ * C_;  // [32][2048][2048]

  prep_kernel<<<8192, 256, 0, stream>>>(x, W_qkv, W_out, xb, wqkvT, woutT);
  gemm_kernel<0, 128><<<dim3(24, 32), 256, 0, stream>>>(xb, wqkvT, b_qkv, q_ws, k_ws, vt_ws,
                                                        nullptr);
  attn_kernel<<<512, 512, 0, stream>>>(q_ws, k_ws, vt_ws, att_out, yh_ws);
  gemm_kernel<1, 64><<<dim3(16, 32), 256, 0, stream>>>(yh_ws, woutT, b_out, nullptr, nullptr,
                                                       nullptr, y_out);
}

// Round 16
// 239.429 us; speedup vs baseline: 1.2169x; 1.2169x over previous
//
#include <hip/hip_runtime.h>

#define B_ 2
#define T_ 2048
#define C_ 1024
#define H_ 16
#define DH_ 64
#define N3_ 3072
#define BT_ 4096   // B_*T_

typedef __attribute__((ext_vector_type(4))) float f32x4;
typedef __attribute__((ext_vector_type(8))) short short8;
typedef __attribute__((ext_vector_type(4))) unsigned short us4;
typedef __attribute__((ext_vector_type(4))) unsigned int u32x4;

// HW bf16 convert (RNE)
__device__ __forceinline__ unsigned short f2bf(float f) {
  return __builtin_bit_cast(unsigned short, (__bf16)f);
}

__device__ __forceinline__ float bf2f(unsigned short s) {
  unsigned int u = ((unsigned int)s) << 16;
  return __builtin_bit_cast(float, u);
}

// pack 2 f32 -> 2 bf16 in one u32 (lo = a, hi = b)
__device__ __forceinline__ unsigned int cvtpk(float a, float b) {
  unsigned int r;
  asm("v_cvt_pk_bf16_f32 %0, %1, %2" : "=v"(r) : "v"(a), "v"(b));
  return r;
}

__device__ __forceinline__ void gload16(const void* g, void* l) {
  __builtin_amdgcn_global_load_lds(
      (const __attribute__((address_space(1))) unsigned int*)g,
      (__attribute__((address_space(3))) unsigned int*)l, 16, 0, 0);
}

// exp scale: 1/sqrt(64) * log2(e), folded into q so softmax exp becomes bare v_exp_f32 (exp2)
#define QSCALE 0.1803368801111137f

// ---------------- K0: fused prep (x cvt + both W transposes) ----------------
__global__ __launch_bounds__(256) void prep_kernel(const float* __restrict__ x,
                                                   const float* __restrict__ W_qkv,
                                                   const float* __restrict__ W_out,
                                                   unsigned short* __restrict__ xb,
                                                   unsigned short* __restrict__ wqkvT,
                                                   unsigned short* __restrict__ woutT) {
  __shared__ float tile[32][33];
  int b = blockIdx.x;
  if (b < 4096) {
    size_t i = (size_t)b * 256 + threadIdx.x;
    float4 v = *(const float4*)(x + i * 4);
    us4 o = {f2bf(v.x), f2bf(v.y), f2bf(v.z), f2bf(v.w)};
    *(us4*)(xb + i * 4) = o;
    return;
  }
  const float* W;
  unsigned short* Wt;
  int Ncols, bx, by;
  if (b < 4096 + 3072) {
    int bb = b - 4096;
    W = W_qkv; Wt = wqkvT; Ncols = 3072; bx = bb % 96; by = bb / 96;
  } else {
    int bb = b - 7168;
    W = W_out; Wt = woutT; Ncols = 1024; bx = bb % 32; by = bb / 32;
  }
  int n0 = bx * 32, k0 = by * 32;
  int tx = threadIdx.x & 31, ty = threadIdx.x >> 5;
#pragma unroll
  for (int i = 0; i < 4; ++i) {
    int k = k0 + ty + i * 8;
    tile[ty + i * 8][tx] = W[(size_t)k * Ncols + n0 + tx];
  }
  __syncthreads();
#pragma unroll
  for (int i = 0; i < 4; ++i) {
    int n = n0 + ty + i * 8;
    Wt[(size_t)n * 1024 + k0 + tx] = f2bf(tile[tx][ty + i * 8]);
  }
}

// ---------------- K1/K3: 128xBN x32 bf16 MFMA GEMM (R6 BK=32 version) ----------------
template <int MODE, int BN>
__global__ __launch_bounds__(256) void gemm_kernel(
    const unsigned short* __restrict__ A, const unsigned short* __restrict__ Bt,
    const float* __restrict__ bias, unsigned short* __restrict__ q_ws,
    unsigned short* __restrict__ k_ws, unsigned short* __restrict__ vt_ws,
    float* __restrict__ yout) {
  __shared__ unsigned short lds_a[128 * 32];
  __shared__ unsigned short lds_b[BN * 32];
  const int tid = threadIdx.x;
  const int w = tid >> 6, l = tid & 63;
  const int m0 = blockIdx.y * 128;
  const int n0 = blockIdx.x * BN;
  const int wr = (w >> 1) * 64, wc = (w & 1) * (BN / 2);
  constexpr int NI = BN / 32;
  const int K = 1024;

  f32x4 acc[4][NI] = {};
  for (int k0 = 0; k0 < K; k0 += 32) {
    __syncthreads();
#pragma unroll
    for (int i = 0; i < 2; ++i) {
      int li = i * 256 + tid;
      int row = li >> 2, cl = li & 3, cs = cl ^ (row & 3);
      gload16((const char*)A + ((size_t)(m0 + row) * K + k0) * 2 + cs * 16,
              (char*)lds_a + li * 16);
    }
#pragma unroll
    for (int i = 0; i < BN / 64; ++i) {
      int li = i * 256 + tid;
      int row = li >> 2, cl = li & 3, cs = cl ^ (row & 3);
      gload16((const char*)Bt + ((size_t)(n0 + row) * K + k0) * 2 + cs * 16,
              (char*)lds_b + li * 16);
    }
    __syncthreads();
    short8 af[4], bfr[NI];
#pragma unroll
    for (int mi = 0; mi < 4; ++mi) {
      int m = wr + mi * 16 + (l & 15);
      af[mi] = *(const short8*)((const char*)lds_a + m * 64 + (((l >> 4) ^ (m & 3)) * 16));
    }
#pragma unroll
    for (int ni = 0; ni < NI; ++ni) {
      int n = wc + ni * 16 + (l & 15);
      bfr[ni] = *(const short8*)((const char*)lds_b + n * 64 + (((l >> 4) ^ (n & 3)) * 16));
    }
#pragma unroll
    for (int mi = 0; mi < 4; ++mi)
#pragma unroll
      for (int ni = 0; ni < NI; ++ni)
        acc[mi][ni] = __builtin_amdgcn_mfma_f32_16x16x32_bf16(af[mi], bfr[ni], acc[mi][ni], 0, 0, 0);
  }

  float bi[NI];
#pragma unroll
  for (int ni = 0; ni < NI; ++ni) bi[ni] = bias[n0 + wc + ni * 16 + (l & 15)];

  if (MODE == 1) {
#pragma unroll
    for (int mi = 0; mi < 4; ++mi) {
#pragma unroll
      for (int ni = 0; ni < NI; ++ni) {
        int n = n0 + wc + ni * 16 + (l & 15);
#pragma unroll
        for (int r = 0; r < 4; ++r) {
          int m = m0 + wr + mi * 16 + ((l >> 4) << 2) + r;
          yout[(size_t)m * 1024 + n] = acc[mi][ni][r] + bi[ni];
        }
      }
    }
  } else {
    int sec = (n0 + wc) >> 10;  // uniform per half-tile: 0=q 1=k 2=v
#pragma unroll
    for (int mi = 0; mi < 4; ++mi) {
#pragma unroll
      for (int ni = 0; ni < NI; ++ni) {
        int n = n0 + wc + ni * 16 + (l & 15);
        int nn = n & 1023, h = nn >> 6, d = nn & 63;
        if (sec == 2) {
          int mbase = m0 + wr + mi * 16 + ((l >> 4) << 2);
          int bb = mbase >> 11, t = mbase & 2047;
          us4 o;
#pragma unroll
          for (int r = 0; r < 4; ++r) o[r] = f2bf(acc[mi][ni][r] + bi[ni]);
          *(us4*)(vt_ws + ((size_t)(bb * 16 + h) * 64 + d) * 2048 + t) = o;
        } else {
#pragma unroll
          for (int r = 0; r < 4; ++r) {
            int m = m0 + wr + mi * 16 + ((l >> 4) << 2) + r;
            int bb = m >> 11, t = m & 2047;
            float v = acc[mi][ni][r] + bi[ni];
            size_t idx = ((size_t)(bb * 16 + h) * 2048 + t) * 64 + d;
            if (sec == 0)
              q_ws[idx] = f2bf(v * QSCALE);  // fold 1/sqrt(64)*log2e into q
            else
              k_ws[idx] = f2bf(v);
          }
        }
      }
    }
  }
}

// ---------------- K2: causal attention, swapped QK^T, dbuf K/V, loads-before-stores,
//                  counted vmcnt(4) keeps att stores off the critical path ----------------
__global__ __launch_bounds__(512) void attn_kernel(
    const unsigned short* __restrict__ q_ws, const unsigned short* __restrict__ k_ws,
    const unsigned short* __restrict__ vt_ws, float* __restrict__ att,
    unsigned short* __restrict__ yh) {
  __shared__ unsigned short lds_k[2][64 * 64];
  __shared__ unsigned short lds_v[2][64 * 64];
  const int tid = threadIdx.x, w = tid >> 6, l = tid & 63;
  const int id = blockIdx.x;
  const int rr = id >> 8, j = id & 255;
  int qt = j & 15;
  if (rr) qt = 15 - qt;
  const int bh = (j >> 4) + (rr << 4);
  const int q0 = qt * 128;
  const size_t hoff = (size_t)bh * (2048 * 64);
  const char* kbase = (const char*)k_ws + hoff * 2;
  const char* vbase = (const char*)vt_ws + hoff * 2;
  float* attb = att + (size_t)bh * 2048 * 2048;

  auto stageK = [&](int kt, int buf) {
    int row = tid >> 3, cl = tid & 7, cs = cl ^ (row & 7);
    gload16(kbase + (size_t)kt * 8192 + row * 128 + cs * 16, (char*)lds_k[buf] + tid * 16);
  };
  auto stageV = [&](int kt, int buf) {
    int row = tid >> 3, cl = tid & 7, cs = cl ^ (row & 7);
    gload16(vbase + (size_t)row * 4096 + kt * 128 + cs * 16, (char*)lds_v[buf] + tid * 16);
  };

  short8 qf[2];
  {
    int row = q0 + w * 16 + (l & 15);
    const char* qb = (const char*)q_ws + (hoff + (size_t)row * 64) * 2;
    qf[0] = *(const short8*)(qb + ((l >> 4) * 16));
    qf[1] = *(const short8*)(qb + 64 + ((l >> 4) * 16));
  }

  // swapped layout: this lane's q-row and per-value k-cols
  const int qrow = q0 + w * 16 + (l & 15);          // q-row owned by this lane (C col index)
  const int kcolbase = (l >> 4) << 2;               // + ni*16 + r gives local k-col
  const int nkt = 2 * qt + 2;

  // ---- pass 1: per-lane scalar row-sum of exp2(s'); prefetch dbuf, 1 barrier/iter ----
  float lsum = 0.f;
  stageK(0, 0);
  asm volatile("s_waitcnt vmcnt(0)" ::: "memory");
  __builtin_amdgcn_s_barrier();
  for (int kt = 0; kt < nkt; ++kt) {
    const int cur = kt & 1;
    if (kt + 1 < nkt) stageK(kt + 1, cur ^ 1);  // prefetch overlaps compute below
    const bool diag = (kt >= 2 * qt);
    f32x4 s[4] = {};
#pragma unroll
    for (int ni = 0; ni < 4; ++ni) {
      int jj = ni * 16 + (l & 15);
#pragma unroll
      for (int cc = 0; cc < 2; ++cc) {
        short8 kf = *(const short8*)((const char*)lds_k[cur] + jj * 128 +
                                     (((cc * 4 + (l >> 4)) ^ (jj & 7)) * 16));
        s[ni] = __builtin_amdgcn_mfma_f32_16x16x32_bf16(kf, qf[cc], s[ni], 0, 0, 0);
      }
    }
#pragma unroll
    for (int ni = 0; ni < 4; ++ni) {
#pragma unroll
      for (int r = 0; r < 4; ++r) {
        float e = __builtin_exp2f(s[ni][r]);
        if (diag) {
          int colg = kt * 64 + ni * 16 + kcolbase + r;
          if (colg > qrow) e = 0.f;
        }
        lsum += e;
      }
    }
    if (kt + 1 < nkt) {  // prefetch load done; no stores exist in pass 1
      asm volatile("s_waitcnt vmcnt(0)" ::: "memory");
      __builtin_amdgcn_s_barrier();
    }
  }

  // row q (=l&15 group) lives in lanes {q, q+16, q+32, q+48}: 2-shuffle reduce
  lsum += __shfl_xor(lsum, 16);
  lsum += __shfl_xor(lsum, 32);
  const float invl = 1.0f / lsum;  // lane-native for q-row (l&15)

  // ---- pass 2: prefetch loads issued BEFORE this iter's stores; vmcnt(4) at the
  //      barrier retires only the (older) loads — the 4 att stores stream on ----
  f32x4 yacc[4] = {};
  const int srcA = (l & 15) + ((l >> 4) & 1) * 32;  // holder of t=0..3 cell
  const int srcB = srcA + 16;                        // holder of t=4..7 cell
  const bool hiSel = ((l >> 4) >> 1) & 1;            // hi>=2 consumers take ni=2kk+1

  stageK(0, 0);
  stageV(0, 0);
  asm volatile("s_waitcnt vmcnt(0)" ::: "memory");
  __builtin_amdgcn_s_barrier();
  for (int kt = 0; kt < nkt; ++kt) {
    const int cur = kt & 1;
    if (kt + 1 < nkt) { stageK(kt + 1, cur ^ 1); stageV(kt + 1, cur ^ 1); }  // loads first
    const bool diag = (kt >= 2 * qt);
    f32x4 s[4] = {};
#pragma unroll
    for (int ni = 0; ni < 4; ++ni) {
      int jj = ni * 16 + (l & 15);
#pragma unroll
      for (int cc = 0; cc < 2; ++cc) {
        short8 kf = *(const short8*)((const char*)lds_k[cur] + jj * 128 +
                                     (((cc * 4 + (l >> 4)) ^ (jj & 7)) * 16));
        s[ni] = __builtin_amdgcn_mfma_f32_16x16x32_bf16(kf, qf[cc], s[ni], 0, 0, 0);
      }
    }
    // normalize, mask, store att (float4 of 4 consecutive cols), pack bf16 pairs
    unsigned int W0[4], W1[4];
#pragma unroll
    for (int ni = 0; ni < 4; ++ni) {
      f32x4 p;
#pragma unroll
      for (int r = 0; r < 4; ++r) {
        float v = __builtin_exp2f(s[ni][r]) * invl;
        if (diag) {
          int colg = kt * 64 + ni * 16 + kcolbase + r;
          if (colg > qrow) v = 0.f;
        }
        p[r] = v;
      }
      *(f32x4*)(attb + (size_t)qrow * 2048 + kt * 64 + ni * 16 + kcolbase) = p;
      W0[ni] = cvtpk(p[0], p[1]);
      W1[ni] = cvtpk(p[2], p[3]);
    }
    // redistribute P into PV A-fragments:
    // consumer (q=l&15, hi=l>>4), col c = kk*32+hi*8+t: source reg ni=2kk+(hi>>1),
    // source lane q+32*(hi&1) for t<4 (srcA) else +16 (srcB), W0/W1 by t&3.
#pragma unroll
    for (int kk = 0; kk < 2; ++kk) {
      unsigned int a0 = __shfl(W0[2 * kk], srcA), a0b = __shfl(W0[2 * kk + 1], srcA);
      unsigned int a1 = __shfl(W1[2 * kk], srcA), a1b = __shfl(W1[2 * kk + 1], srcA);
      unsigned int b0 = __shfl(W0[2 * kk], srcB), b0b = __shfl(W0[2 * kk + 1], srcB);
      unsigned int b1 = __shfl(W1[2 * kk], srcB), b1b = __shfl(W1[2 * kk + 1], srcB);
      u32x4 F = {hiSel ? a0b : a0, hiSel ? a1b : a1, hiSel ? b0b : b0, hiSel ? b1b : b1};
      short8 pf = __builtin_bit_cast(short8, F);
#pragma unroll
      for (int ni = 0; ni < 4; ++ni) {
        int d = ni * 16 + (l & 15);
        short8 vf = *(const short8*)((const char*)lds_v[cur] + d * 128 +
                                     (((kk * 4 + (l >> 4)) ^ (d & 7)) * 16));
        yacc[ni] = __builtin_amdgcn_mfma_f32_16x16x32_bf16(pf, vf, yacc[ni], 0, 0, 0);
      }
    }
    if (kt + 1 < nkt) {
      // in-order vmcnt: ≤4 outstanding forces the 2 older prefetch loads done;
      // this iter's 4 att stores (newest) keep streaming across the barrier.
      asm volatile("s_waitcnt vmcnt(4)" ::: "memory");
      __builtin_amdgcn_s_barrier();
    }
  }

  // y_heads write: [B][T][H*64] bf16 (yacc already normalized — P carried invl)
  {
    int bb = bh >> 4, h = bh & 15;
#pragma unroll
    for (int ni = 0; ni < 4; ++ni) {
      int d = ni * 16 + (l & 15);
#pragma unroll
      for (int r = 0; r < 4; ++r) {
        int t = q0 + w * 16 + ((l >> 4) << 2) + r;
        yh[((size_t)bb * 2048 + t) * 1024 + h * 64 + d] = f2bf(yacc[ni][r]);
      }
    }
  }

  // zero the strictly-upper region beyond this q-tile's band
  int cstart = q0 + 128;
  if (cstart < 2048) {
    int nz = 2048 - cstart;
    float4 z = make_float4(0.f, 0.f, 0.f, 0.f);
    for (int row = 0; row < 128; ++row) {
      float* dst = attb + (size_t)(q0 + row) * 2048 + cstart;
      for (int c = tid * 4; c < nz; c += 2048) *(float4*)(dst + c) = z;
    }
  }
}

// ---------------- launch ----------------
extern "C" void kernel_launch(void* const* d_in, const int* in_sizes, int n_in,
                              void* d_out, int out_size, void* d_ws, size_t ws_size,
                              hipStream_t stream) {
  const float* x = (const float*)d_in[0];
  const float* W_qkv = (const float*)d_in[1];
  const float* b_qkv = (const float*)d_in[2];
  const float* W_out = (const float*)d_in[3];
  const float* b_out = (const float*)d_in[4];
  float* out = (float*)d_out;

  char* ws = (char*)d_ws;
  unsigned short* xb = (unsigned short*)(ws);                        // 8 MB
  unsigned short* wqkvT = (unsigned short*)(ws + 8388608);           // 6 MB
  unsigned short* woutT = (unsigned short*)(ws + 14680064);          // 2 MB
  unsigned short* q_ws = (unsigned short*)(ws + 16777216);           // 8 MB
  unsigned short* k_ws = (unsigned short*)(ws + 25165824);           // 8 MB
  unsigned short* vt_ws = (unsigned short*)(ws + 33554432);          // 8 MB
  unsigned short* yh_ws = (unsigned short*)(ws + 41943040);          // 8 MB

  float* y_out = out;                       // [4096][1024]
  float* att_out = out + (size_t)BT_ * C_;  // [32][2048][2048]

  prep_kernel<<<8192, 256, 0, stream>>>(x, W_qkv, W_out, xb, wqkvT, woutT);
  gemm_kernel<0, 128><<<dim3(24, 32), 256, 0, stream>>>(xb, wqkvT, b_qkv, q_ws, k_ws, vt_ws,
                                                        nullptr);
  attn_kernel<<<512, 512, 0, stream>>>(q_ws, k_ws, vt_ws, att_out, yh_ws);
  gemm_kernel<1, 64><<<dim3(16, 32), 256, 0, stream>>>(yh_ws, woutT, b_out, nullptr, nullptr,
                                                       nullptr, y_out);
}

// Round 17
// 212.842 us; speedup vs baseline: 1.3689x; 1.1249x over previous
//
#include <hip/hip_runtime.h>

#define B_ 2
#define T_ 2048
#define C_ 1024
#define H_ 16
#define DH_ 64
#define N3_ 3072
#define BT_ 4096   // B_*T_

typedef __attribute__((ext_vector_type(4))) float f32x4;
typedef __attribute__((ext_vector_type(8))) short short8;
typedef __attribute__((ext_vector_type(4))) unsigned short us4;
typedef __attribute__((ext_vector_type(4))) unsigned int u32x4;

// HW bf16 convert (RNE)
__device__ __forceinline__ unsigned short f2bf(float f) {
  return __builtin_bit_cast(unsigned short, (__bf16)f);
}

__device__ __forceinline__ float bf2f(unsigned short s) {
  unsigned int u = ((unsigned int)s) << 16;
  return __builtin_bit_cast(float, u);
}

// pack 2 f32 -> 2 bf16 in one u32 (lo = a, hi = b)
__device__ __forceinline__ unsigned int cvtpk(float a, float b) {
  unsigned int r;
  asm("v_cvt_pk_bf16_f32 %0, %1, %2" : "=v"(r) : "v"(a), "v"(b));
  return r;
}

__device__ __forceinline__ void gload16(const void* g, void* l) {
  __builtin_amdgcn_global_load_lds(
      (const __attribute__((address_space(1))) unsigned int*)g,
      (__attribute__((address_space(3))) unsigned int*)l, 16, 0, 0);
}

// exp scale: 1/sqrt(64) * log2(e), folded into q so softmax exp becomes bare v_exp_f32 (exp2)
#define QSCALE 0.1803368801111137f

// ---------------- K0: fused prep (x cvt + both W transposes) ----------------
__global__ __launch_bounds__(256) void prep_kernel(const float* __restrict__ x,
                                                   const float* __restrict__ W_qkv,
                                                   const float* __restrict__ W_out,
                                                   unsigned short* __restrict__ xb,
                                                   unsigned short* __restrict__ wqkvT,
                                                   unsigned short* __restrict__ woutT) {
  __shared__ float tile[32][33];
  int b = blockIdx.x;
  if (b < 4096) {
    size_t i = (size_t)b * 256 + threadIdx.x;
    float4 v = *(const float4*)(x + i * 4);
    us4 o = {f2bf(v.x), f2bf(v.y), f2bf(v.z), f2bf(v.w)};
    *(us4*)(xb + i * 4) = o;
    return;
  }
  const float* W;
  unsigned short* Wt;
  int Ncols, bx, by;
  if (b < 4096 + 3072) {
    int bb = b - 4096;
    W = W_qkv; Wt = wqkvT; Ncols = 3072; bx = bb % 96; by = bb / 96;
  } else {
    int bb = b - 7168;
    W = W_out; Wt = woutT; Ncols = 1024; bx = bb % 32; by = bb / 32;
  }
  int n0 = bx * 32, k0 = by * 32;
  int tx = threadIdx.x & 31, ty = threadIdx.x >> 5;
#pragma unroll
  for (int i = 0; i < 4; ++i) {
    int k = k0 + ty + i * 8;
    tile[ty + i * 8][tx] = W[(size_t)k * Ncols + n0 + tx];
  }
  __syncthreads();
#pragma unroll
  for (int i = 0; i < 4; ++i) {
    int n = n0 + ty + i * 8;
    Wt[(size_t)n * 1024 + k0 + tx] = f2bf(tile[tx][ty + i * 8]);
  }
}

// ---------------- K1/K3: 128xBN x32 bf16 MFMA GEMM (R6 BK=32 version) ----------------
template <int MODE, int BN>
__global__ __launch_bounds__(256) void gemm_kernel(
    const unsigned short* __restrict__ A, const unsigned short* __restrict__ Bt,
    const float* __restrict__ bias, unsigned short* __restrict__ q_ws,
    unsigned short* __restrict__ k_ws, unsigned short* __restrict__ vt_ws,
    float* __restrict__ yout) {
  __shared__ unsigned short lds_a[128 * 32];
  __shared__ unsigned short lds_b[BN * 32];
  const int tid = threadIdx.x;
  const int w = tid >> 6, l = tid & 63;
  const int m0 = blockIdx.y * 128;
  const int n0 = blockIdx.x * BN;
  const int wr = (w >> 1) * 64, wc = (w & 1) * (BN / 2);
  constexpr int NI = BN / 32;
  const int K = 1024;

  f32x4 acc[4][NI] = {};
  for (int k0 = 0; k0 < K; k0 += 32) {
    __syncthreads();
#pragma unroll
    for (int i = 0; i < 2; ++i) {
      int li = i * 256 + tid;
      int row = li >> 2, cl = li & 3, cs = cl ^ (row & 3);
      gload16((const char*)A + ((size_t)(m0 + row) * K + k0) * 2 + cs * 16,
              (char*)lds_a + li * 16);
    }
#pragma unroll
    for (int i = 0; i < BN / 64; ++i) {
      int li = i * 256 + tid;
      int row = li >> 2, cl = li & 3, cs = cl ^ (row & 3);
      gload16((const char*)Bt + ((size_t)(n0 + row) * K + k0) * 2 + cs * 16,
              (char*)lds_b + li * 16);
    }
    __syncthreads();
    short8 af[4], bfr[NI];
#pragma unroll
    for (int mi = 0; mi < 4; ++mi) {
      int m = wr + mi * 16 + (l & 15);
      af[mi] = *(const short8*)((const char*)lds_a + m * 64 + (((l >> 4) ^ (m & 3)) * 16));
    }
#pragma unroll
    for (int ni = 0; ni < NI; ++ni) {
      int n = wc + ni * 16 + (l & 15);
      bfr[ni] = *(const short8*)((const char*)lds_b + n * 64 + (((l >> 4) ^ (n & 3)) * 16));
    }
#pragma unroll
    for (int mi = 0; mi < 4; ++mi)
#pragma unroll
      for (int ni = 0; ni < NI; ++ni)
        acc[mi][ni] = __builtin_amdgcn_mfma_f32_16x16x32_bf16(af[mi], bfr[ni], acc[mi][ni], 0, 0, 0);
  }

  float bi[NI];
#pragma unroll
  for (int ni = 0; ni < NI; ++ni) bi[ni] = bias[n0 + wc + ni * 16 + (l & 15)];

  if (MODE == 1) {
#pragma unroll
    for (int mi = 0; mi < 4; ++mi) {
#pragma unroll
      for (int ni = 0; ni < NI; ++ni) {
        int n = n0 + wc + ni * 16 + (l & 15);
#pragma unroll
        for (int r = 0; r < 4; ++r) {
          int m = m0 + wr + mi * 16 + ((l >> 4) << 2) + r;
          yout[(size_t)m * 1024 + n] = acc[mi][ni][r] + bi[ni];
        }
      }
    }
  } else {
    int sec = (n0 + wc) >> 10;  // uniform per half-tile: 0=q 1=k 2=v
#pragma unroll
    for (int mi = 0; mi < 4; ++mi) {
#pragma unroll
      for (int ni = 0; ni < NI; ++ni) {
        int n = n0 + wc + ni * 16 + (l & 15);
        int nn = n & 1023, h = nn >> 6, d = nn & 63;
        if (sec == 2) {
          int mbase = m0 + wr + mi * 16 + ((l >> 4) << 2);
          int bb = mbase >> 11, t = mbase & 2047;
          us4 o;
#pragma unroll
          for (int r = 0; r < 4; ++r) o[r] = f2bf(acc[mi][ni][r] + bi[ni]);
          *(us4*)(vt_ws + ((size_t)(bb * 16 + h) * 64 + d) * 2048 + t) = o;
        } else {
#pragma unroll
          for (int r = 0; r < 4; ++r) {
            int m = m0 + wr + mi * 16 + ((l >> 4) << 2) + r;
            int bb = m >> 11, t = m & 2047;
            float v = acc[mi][ni][r] + bi[ni];
            size_t idx = ((size_t)(bb * 16 + h) * 2048 + t) * 64 + d;
            if (sec == 0)
              q_ws[idx] = f2bf(v * QSCALE);  // fold 1/sqrt(64)*log2e into q
            else
              k_ws[idx] = f2bf(v);
          }
        }
      }
    }
  }
}

// ---------------- K2: causal attention, swapped QK^T; pass1 KVBLK=128 (aliased LDS),
//                  pass2 KVBLK=64 dbuf + counted vmcnt(4) (R16 schedule) ----------------
__global__ __launch_bounds__(512) void attn_kernel(
    const unsigned short* __restrict__ q_ws, const unsigned short* __restrict__ k_ws,
    const unsigned short* __restrict__ vt_ws, float* __restrict__ att,
    unsigned short* __restrict__ yh) {
  // 2 x 16 KB buffers. Pass 1: each = one 128x64 bf16 K tile.
  // Pass 2: each = 64x64 K tile (first 8 KB) + 64x64 V tile (second 8 KB).
  __shared__ unsigned short lds_all[2][8192];
  const int tid = threadIdx.x, w = tid >> 6, l = tid & 63;
  const int id = blockIdx.x;
  const int rr = id >> 8, j = id & 255;
  int qt = j & 15;
  if (rr) qt = 15 - qt;
  const int bh = (j >> 4) + (rr << 4);
  const int q0 = qt * 128;
  const size_t hoff = (size_t)bh * (2048 * 64);
  const char* kbase = (const char*)k_ws + hoff * 2;
  const char* vbase = (const char*)vt_ws + hoff * 2;
  float* attb = att + (size_t)bh * 2048 * 2048;

  // pass-1 staging: 128x64 K tile (16 KB), 2 x 16B chunks/thread
  auto stageK128 = [&](int kt, int buf) {
#pragma unroll
    for (int i = 0; i < 2; ++i) {
      int li = i * 512 + tid;
      int row = li >> 3, cl = li & 7, cs = cl ^ (row & 7);
      gload16(kbase + ((size_t)kt * 128 + row) * 128 + cs * 16, (char*)lds_all[buf] + li * 16);
    }
  };
  // pass-2 staging: 64x64 tiles, 1 chunk/thread
  auto stageK64 = [&](int kt, int buf) {
    int row = tid >> 3, cl = tid & 7, cs = cl ^ (row & 7);
    gload16(kbase + (size_t)kt * 8192 + row * 128 + cs * 16, (char*)lds_all[buf] + tid * 16);
  };
  auto stageV64 = [&](int kt, int buf) {
    int row = tid >> 3, cl = tid & 7, cs = cl ^ (row & 7);
    gload16(vbase + (size_t)row * 4096 + kt * 128 + cs * 16,
            (char*)lds_all[buf] + 8192 + tid * 16);
  };

  short8 qf[2];
  {
    int row = q0 + w * 16 + (l & 15);
    const char* qb = (const char*)q_ws + (hoff + (size_t)row * 64) * 2;
    qf[0] = *(const short8*)(qb + ((l >> 4) * 16));
    qf[1] = *(const short8*)(qb + 64 + ((l >> 4) * 16));
  }

  // swapped layout: this lane's q-row and per-value k-cols
  const int qrow = q0 + w * 16 + (l & 15);          // q-row owned by this lane (C col index)
  const int kcolbase = (l >> 4) << 2;               // + ni*16 + r gives local k-col

  // ---- pass 1: per-lane scalar row-sum of exp2(s') over 128-wide K tiles ----
  float lsum = 0.f;
  const int nkt1 = qt + 1;
  stageK128(0, 0);
  asm volatile("s_waitcnt vmcnt(0)" ::: "memory");
  __builtin_amdgcn_s_barrier();
  for (int kt = 0; kt < nkt1; ++kt) {
    const int cur = kt & 1;
    if (kt + 1 < nkt1) stageK128(kt + 1, cur ^ 1);  // prefetch overlaps compute
    const bool diag = (kt == qt);
    f32x4 s[8];
#pragma unroll
    for (int ni = 0; ni < 8; ++ni) s[ni] = f32x4{0.f, 0.f, 0.f, 0.f};
#pragma unroll
    for (int ni = 0; ni < 8; ++ni) {
      int jj = ni * 16 + (l & 15);  // k-row 0..127
#pragma unroll
      for (int cc = 0; cc < 2; ++cc) {
        short8 kf = *(const short8*)((const char*)lds_all[cur] + jj * 128 +
                                     (((cc * 4 + (l >> 4)) ^ (jj & 7)) * 16));
        s[ni] = __builtin_amdgcn_mfma_f32_16x16x32_bf16(kf, qf[cc], s[ni], 0, 0, 0);
      }
    }
#pragma unroll
    for (int ni = 0; ni < 8; ++ni) {
#pragma unroll
      for (int r = 0; r < 4; ++r) {
        float e = __builtin_exp2f(s[ni][r]);
        if (diag) {
          int colg = kt * 128 + ni * 16 + kcolbase + r;
          if (colg > qrow) e = 0.f;
        }
        lsum += e;
      }
    }
    if (kt + 1 < nkt1) {  // prefetch load done; no stores exist in pass 1
      asm volatile("s_waitcnt vmcnt(0)" ::: "memory");
      __builtin_amdgcn_s_barrier();
    }
  }

  // row q (=l&15 group) lives in lanes {q, q+16, q+32, q+48}: 2-shuffle reduce
  lsum += __shfl_xor(lsum, 16);
  lsum += __shfl_xor(lsum, 32);
  const float invl = 1.0f / lsum;  // lane-native for q-row (l&15)

  // all waves done reading pass-1 tiles before pass-2 staging overwrites them
  __syncthreads();

  // ---- pass 2: prefetch loads issued BEFORE this iter's stores; vmcnt(4) at the
  //      barrier retires only the (older) loads — the 4 att stores stream on ----
  f32x4 yacc[4] = {};
  const int srcA = (l & 15) + ((l >> 4) & 1) * 32;  // holder of t=0..3 cell
  const int srcB = srcA + 16;                        // holder of t=4..7 cell
  const bool hiSel = ((l >> 4) >> 1) & 1;            // hi>=2 consumers take ni=2kk+1
  const int nkt = 2 * qt + 2;

  stageK64(0, 0);
  stageV64(0, 0);
  asm volatile("s_waitcnt vmcnt(0)" ::: "memory");
  __builtin_amdgcn_s_barrier();
  for (int kt = 0; kt < nkt; ++kt) {
    const int cur = kt & 1;
    if (kt + 1 < nkt) { stageK64(kt + 1, cur ^ 1); stageV64(kt + 1, cur ^ 1); }  // loads first
    const bool diag = (kt >= 2 * qt);
    f32x4 s[4] = {};
#pragma unroll
    for (int ni = 0; ni < 4; ++ni) {
      int jj = ni * 16 + (l & 15);
#pragma unroll
      for (int cc = 0; cc < 2; ++cc) {
        short8 kf = *(const short8*)((const char*)lds_all[cur] + jj * 128 +
                                     (((cc * 4 + (l >> 4)) ^ (jj & 7)) * 16));
        s[ni] = __builtin_amdgcn_mfma_f32_16x16x32_bf16(kf, qf[cc], s[ni], 0, 0, 0);
      }
    }
    // normalize, mask, store att (float4 of 4 consecutive cols), pack bf16 pairs
    unsigned int W0[4], W1[4];
#pragma unroll
    for (int ni = 0; ni < 4; ++ni) {
      f32x4 p;
#pragma unroll
      for (int r = 0; r < 4; ++r) {
        float v = __builtin_exp2f(s[ni][r]) * invl;
        if (diag) {
          int colg = kt * 64 + ni * 16 + kcolbase + r;
          if (colg > qrow) v = 0.f;
        }
        p[r] = v;
      }
      *(f32x4*)(attb + (size_t)qrow * 2048 + kt * 64 + ni * 16 + kcolbase) = p;
      W0[ni] = cvtpk(p[0], p[1]);
      W1[ni] = cvtpk(p[2], p[3]);
    }
    // redistribute P into PV A-fragments:
    // consumer (q=l&15, hi=l>>4), col c = kk*32+hi*8+t: source reg ni=2kk+(hi>>1),
    // source lane q+32*(hi&1) for t<4 (srcA) else +16 (srcB), W0/W1 by t&3.
#pragma unroll
    for (int kk = 0; kk < 2; ++kk) {
      unsigned int a0 = __shfl(W0[2 * kk], srcA), a0b = __shfl(W0[2 * kk + 1], srcA);
      unsigned int a1 = __shfl(W1[2 * kk], srcA), a1b = __shfl(W1[2 * kk + 1], srcA);
      unsigned int b0 = __shfl(W0[2 * kk], srcB), b0b = __shfl(W0[2 * kk + 1], srcB);
      unsigned int b1 = __shfl(W1[2 * kk], srcB), b1b = __shfl(W1[2 * kk + 1], srcB);
      u32x4 F = {hiSel ? a0b : a0, hiSel ? a1b : a1, hiSel ? b0b : b0, hiSel ? b1b : b1};
      short8 pf = __builtin_bit_cast(short8, F);
#pragma unroll
      for (int ni = 0; ni < 4; ++ni) {
        int d = ni * 16 + (l & 15);
        short8 vf = *(const short8*)((const char*)lds_all[cur] + 8192 + d * 128 +
                                     (((kk * 4 + (l >> 4)) ^ (d & 7)) * 16));
        yacc[ni] = __builtin_amdgcn_mfma_f32_16x16x32_bf16(pf, vf, yacc[ni], 0, 0, 0);
      }
    }
    if (kt + 1 < nkt) {
      // in-order vmcnt: ≤4 outstanding forces the 2 older prefetch loads done;
      // this iter's 4 att stores (newest) keep streaming across the barrier.
      asm volatile("s_waitcnt vmcnt(4)" ::: "memory");
      __builtin_amdgcn_s_barrier();
    }
  }

  // y_heads write: [B][T][H*64] bf16 (yacc already normalized — P carried invl)
  {
    int bb = bh >> 4, h = bh & 15;
#pragma unroll
    for (int ni = 0; ni < 4; ++ni) {
      int d = ni * 16 + (l & 15);
#pragma unroll
      for (int r = 0; r < 4; ++r) {
        int t = q0 + w * 16 + ((l >> 4) << 2) + r;
        yh[((size_t)bb * 2048 + t) * 1024 + h * 64 + d] = f2bf(yacc[ni][r]);
      }
    }
  }

  // zero the strictly-upper region beyond this q-tile's band
  int cstart = q0 + 128;
  if (cstart < 2048) {
    int nz = 2048 - cstart;
    float4 z = make_float4(0.f, 0.f, 0.f, 0.f);
    for (int row = 0; row < 128; ++row) {
      float* dst = attb + (size_t)(q0 + row) * 2048 + cstart;
      for (int c = tid * 4; c < nz; c += 2048) *(float4*)(dst + c) = z;
    }
  }
}

// ---------------- launch ----------------
extern "C" void kernel_launch(void* const* d_in, const int* in_sizes, int n_in,
                              void* d_out, int out_size, void* d_ws, size_t ws_size,
                              hipStream_t stream) {
  const float* x = (const float*)d_in[0];
  const float* W_qkv = (const float*)d_in[1];
  const float* b_qkv = (const float*)d_in[2];
  const float* W_out = (const float*)d_in[3];
  const float* b_out = (const float*)d_in[4];
  float* out = (float*)d_out;

  char* ws = (char*)d_ws;
  unsigned short* xb = (unsigned short*)(ws);                        // 8 MB
  unsigned short* wqkvT = (unsigned short*)(ws + 8388608);           // 6 MB
  unsigned short* woutT = (unsigned short*)(ws + 14680064);          // 2 MB
  unsigned short* q_ws = (unsigned short*)(ws + 16777216);           // 8 MB
  unsigned short* k_ws = (unsigned short*)(ws + 25165824);           // 8 MB
  unsigned short* vt_ws = (unsigned short*)(ws + 33554432);          // 8 MB
  unsigned short* yh_ws = (unsigned short*)(ws + 41943040);          // 8 MB

  float* y_out = out;                       // [4096][1024]
  float* att_out = out + (size_t)BT_ * C_;  // [32][2048][2048]

  prep_kernel<<<8192, 256, 0, stream>>>(x, W_qkv, W_out, xb, wqkvT, woutT);
  gemm_kernel<0, 128><<<dim3(24, 32), 256, 0, stream>>>(xb, wqkvT, b_qkv, q_ws, k_ws, vt_ws,
                                                        nullptr);
  attn_kernel<<<512, 512, 0, stream>>>(q_ws, k_ws, vt_ws, att_out, yh_ws);
  gemm_kernel<1, 64><<<dim3(16, 32), 256, 0, stream>>>(yh_ws, woutT, b_out, nullptr, nullptr,
                                                       nullptr, y_out);
}